// Round 4
// baseline (872.651 us; speedup 1.0000x reference)
//
#include <hip/hip_runtime.h>

// B=16,S=1024,E=1024,F=4096,H=16,D=64. N = B*S = 16384 tokens.
// Pipeline: LN1 -> QKV gemm(bf16 MFMA)+bias -> MFMA flash attn (S^T softmax) ->
//           proj gemm+bias+resid -> d_out -> LN2 -> lin1 gemm+bias+GELU ->
//           lin2 gemm+bias+resid(in-place d_out). FFN single-pass if ws allows, else 2-chunk.
//
// GEMM engine: PERSISTENT 256x256 tile, BK=64, 512 thr (8 waves 2Mx4N), double-buffered
// 128 KB LDS, 8-phase counted-vmcnt schedule (T3+T4+T5).
// R4: (a) operand-swapped MFMA -> C^T fragments: each thread owns 4 CONSECUTIVE n values
//     -> epilogue is 32x 8B/16B coalesced stores (was 128x scalar), float4 bias/resid;
// (b) 2D XCD chunking (2m x 4n): per XCD a 32m x NC-n tile rectangle, n-fastest within;
//     B working set <= 2 MB (L2-pinned), A duplication 8x -> 4x.
//
// Workspace plan:
//   0          wqkv_b  bf16 3072x1024   (6 MB)
//   6291456    wo_b    bf16 1024x1024   (2 MB)
//   8388608    w1_b    bf16 4096x1024   (8 MB)
//   16777216   w2_b    bf16 1024x4096   (8 MB)
//   25165824   region1 (32 MB): xn_b -> ctx_b -> xn2_b
//   58720256   region2: qkv_b (96 MB) -> h (128 MB single-pass if ws_size>=184MiB,
//                                            else 64 MB chunks, 2-pass)
// x1 (fp32) lives in d_out; lin2 updates d_out in place (same-thread R->W).

typedef __attribute__((ext_vector_type(8))) short bf16x8;
typedef __attribute__((ext_vector_type(4))) float f32x4;
typedef __attribute__((ext_vector_type(8))) unsigned short u16x8;
typedef __attribute__((ext_vector_type(4))) unsigned short u16x4;

__device__ __forceinline__ float bf2f(unsigned short u) {
    return __uint_as_float(((unsigned int)u) << 16);
}
__device__ __forceinline__ unsigned short f2bf(float f) {
    unsigned int u = __float_as_uint(f);
    u += 0x7fffu + ((u >> 16) & 1u);   // RNE
    return (unsigned short)(u >> 16);
}
// pack two positive f32 into bf16x2 dword by truncation (P in [0,1])
__device__ __forceinline__ unsigned int pkbf_trunc(float a, float b) {
    return (__float_as_uint(a) >> 16) | (__float_as_uint(b) & 0xffff0000u);
}

// GELU with A&S 7.1.26 erf (|err| <= 1.5e-7)
__device__ __forceinline__ float fast_gelu(float v) {
    const float x = v * 0.70710678118654752f;
    const float ax = fabsf(x);
    const float t = __builtin_amdgcn_rcpf(fmaf(0.3275911f, ax, 1.0f));
    float p = fmaf(1.061405429f, t, -1.453152027f);
    p = fmaf(p, t, 1.421413741f);
    p = fmaf(p, t, -0.284496736f);
    p = fmaf(p, t, 0.254829592f);
    p = p * t;
    const float e = __expf(-x * x);
    float erfv = fmaf(-p, e, 1.0f);
    erfv = (x < 0.0f) ? -erfv : erfv;
    return 0.5f * v * (1.0f + erfv);
}

// async global->LDS, 16 B per lane; LDS dest is wave-uniform base + lane*16
__device__ __forceinline__ void gload_lds16(const unsigned short* g, unsigned short* l) {
    __builtin_amdgcn_global_load_lds(
        (const __attribute__((address_space(1))) unsigned int*)g,
        (__attribute__((address_space(3))) unsigned int*)l, 16, 0, 0);
}

// compiler memory fence (free) + raw barrier: does NOT drain vmcnt (unlike __syncthreads)
#define FENCE() asm volatile("" ::: "memory")
#define BAR()                         \
    do {                              \
        FENCE();                      \
        __builtin_amdgcn_s_barrier(); \
        FENCE();                      \
    } while (0)
#define VMCNT(n)                                               \
    do {                                                       \
        asm volatile("s_waitcnt vmcnt(" #n ")" ::: "memory");  \
        __builtin_amdgcn_sched_barrier(0);                     \
    } while (0)

// ---------------- fp32 -> bf16 weight conversion ----------------
__global__ __launch_bounds__(256) void cvt_kernel(const float* __restrict__ in,
                                                  unsigned short* __restrict__ out, int n4) {
    int i = blockIdx.x * 256 + threadIdx.x;
    if (i >= n4) return;
    float4 v = ((const float4*)in)[i];
    u16x4 o;
    o[0] = f2bf(v.x); o[1] = f2bf(v.y); o[2] = f2bf(v.z); o[3] = f2bf(v.w);
    ((u16x4*)out)[i] = o;
}

// ---------------- LayerNorm (E=1024), fp32 in -> bf16 out ----------------
__global__ __launch_bounds__(256) void ln_kernel(const float* __restrict__ x,
                                                 const float* __restrict__ w,
                                                 const float* __restrict__ b,
                                                 unsigned short* __restrict__ out) {
    const int row = blockIdx.x;
    const int t = threadIdx.x;
    const float* xr = x + (size_t)row * 1024;
    float4 v = *(const float4*)(xr + t * 4);
    float s = v.x + v.y + v.z + v.w;
    float sq = v.x * v.x + v.y * v.y + v.z * v.z + v.w * v.w;
#pragma unroll
    for (int off = 32; off > 0; off >>= 1) {
        s += __shfl_xor(s, off);
        sq += __shfl_xor(sq, off);
    }
    __shared__ float rs_[4], rq_[4];
    if ((t & 63) == 0) { rs_[t >> 6] = s; rq_[t >> 6] = sq; }
    __syncthreads();
    s = rs_[0] + rs_[1] + rs_[2] + rs_[3];
    sq = rq_[0] + rq_[1] + rq_[2] + rq_[3];
    const float mu = s * (1.0f / 1024.0f);
    const float var = sq * (1.0f / 1024.0f) - mu * mu;
    const float rstd = rsqrtf(var + 1e-5f);
    const int c = t * 4;
    float4 wv = *(const float4*)(w + c);
    float4 bv = *(const float4*)(b + c);
    u16x4 o;
    o[0] = f2bf((v.x - mu) * rstd * wv.x + bv.x);
    o[1] = f2bf((v.y - mu) * rstd * wv.y + bv.y);
    o[2] = f2bf((v.z - mu) * rstd * wv.z + bv.z);
    o[3] = f2bf((v.w - mu) * rstd * wv.w + bv.w);
    *(u16x4*)(out + (size_t)row * 1024 + c) = o;
}

// ---------------- persistent bf16 MFMA GEMM: C[M,N] = A[M,K] @ Bt[N,K]^T ----------------
// Per phase: {ds_read 4-12 x b128 (base+imm) || issue 2x global_load_lds -> s_barrier ->
//             setprio(1) 16x mfma(SWAPPED operands -> C^T frags) setprio(0) -> s_barrier}
// vmcnt(4) at p4/p8 only. Stage order / ledger / WAR identical to the verified R2 engine.
// C^T fragment layout: thread(w,quad,cl): m = wm*128+mf*16+cl ; n = wn*64+nf*16+quad*4+rr
// (rr consecutive in n -> 8B/16B vector stores).
// Tile order: XCD x = g&7 as (xm=x>>2, xn=x&3); XCD owns MC m-tiles x NC n-tiles,
// n-fastest within. l = (g>>3) + tj*(NB/8); mi = l/NC, ni = l%NC.
// EPI: 0 bias->bf16 ; 1 bias+resid->f32 ; 2 bias+GELU->bf16
// Requires M%256==0, N%256==0, K%128==0, K>=256, GY%2==0, (N/256)%4==0,
// nt%gridDim.x==0, gridDim.x%8==0, MC=GY/2, NC=(N/256)/4.
template <int EPI>
__global__ __launch_bounds__(512, 2) void gemm_bt(const unsigned short* __restrict__ A,
                                                  const unsigned short* __restrict__ Bt,
                                                  const float* __restrict__ bias,
                                                  const float* __restrict__ resid,
                                                  void* __restrict__ outp,
                                                  int M, int N, int K, int cnt,
                                                  int NC, int MC) {
    __shared__ __align__(16) unsigned short sA[2][256 * 64];
    __shared__ __align__(16) unsigned short sB[2][256 * 64];
    const int t = threadIdx.x;
    const int lane = t & 63;
    const int w = t >> 6;            // 0..7
    const int wm = w >> 2;           // 0..1  (wave M index)
    const int wn = w & 3;            // 0..3  (wave N index)
    const int quad = lane >> 4;
    const int cl = lane & 15;

    const int NB = gridDim.x;
    const int g = blockIdx.x;
    const int lpb = NB >> 3;         // per-XCD block count (l stride per tile step)
    const int xm = (g >> 2) & 1;     // XCD m-row   (x = g&7 -> xm = bit2, xn = bits0..1)
    const int xn = g & 3;            // XCD n-col
    const int l0 = g >> 3;

    // decode tile ordinal tj -> (mB, nB)
#define DECODE(tjv, mB, nB)                                  \
    do {                                                     \
        const int l_ = l0 + (tjv) * lpb;                     \
        const int mi_ = l_ / NC;                             \
        const int ni_ = l_ - mi_ * NC;                       \
        (mB) = (xm * MC + mi_) << 8;                         \
        (nB) = (xn * NC + ni_) << 8;                         \
    } while (0)

    // ---- precomputed per-thread LDS read bases (byte pointers; reads = base+imm) ----
    const int swz0 = (quad ^ (cl & 7)) * 16;           // ks=0 chunk byte offset
    const int swz1 = ((quad + 4) ^ (cl & 7)) * 16;     // ks=1 chunk byte offset
    const char* aB0 = (const char*)sA + (wm * 128 + cl) * 128 + swz0;
    const char* aB1 = (const char*)sA + (wm * 128 + cl) * 128 + swz1;
    const char* bB0 = (const char*)sB + (wn * 64 + cl) * 128 + swz0;
    const char* bB1 = (const char*)sB + (wn * 64 + cl) * 128 + swz1;

    // ---- precomputed per-thread staging offset (elements): (w*16 + rl)*K + ch ----
    const int rl = lane >> 3;
    const size_t o8 = (size_t)8 * K;
    const size_t o128 = (size_t)128 * K;
    const size_t thr = (size_t)(w * 16 + rl) * K + (size_t)(((lane & 7) ^ rl) * 8);

#define STG(gp, sbuf, buf, hf, k0)                                                        \
    do {                                                                                  \
        gload_lds16((gp) + (k0) + thr + (hf) * o128,                                      \
                    &sbuf[buf][((hf) * 128 + w * 16) * 64]);                              \
        gload_lds16((gp) + (k0) + thr + (hf) * o128 + o8,                                 \
                    &sbuf[buf][((hf) * 128 + w * 16 + 8) * 64]);                          \
    } while (0)
#define READ_B8(buf)                                                                      \
    do {                                                                                  \
        _Pragma("unroll") for (int nf_ = 0; nf_ < 4; ++nf_) {                             \
            bfr[nf_][0] = *(const bf16x8*)(bB0 + (buf) * 32768 + nf_ * 2048);             \
            bfr[nf_][1] = *(const bf16x8*)(bB1 + (buf) * 32768 + nf_ * 2048);             \
        }                                                                                 \
    } while (0)
#define READ_A2(buf, mfb)                                                                 \
    do {                                                                                  \
        af[0][0] = *(const bf16x8*)(aB0 + (buf) * 32768 + (mfb) * 2048);                  \
        af[0][1] = *(const bf16x8*)(aB1 + (buf) * 32768 + (mfb) * 2048);                  \
        af[1][0] = *(const bf16x8*)(aB0 + (buf) * 32768 + ((mfb) + 1) * 2048);            \
        af[1][1] = *(const bf16x8*)(aB1 + (buf) * 32768 + ((mfb) + 1) * 2048);            \
    } while (0)
// SWAPPED operands: D^T fragments (A/B frag layouts identical for 16x16x32)
#define MFMA_Q(q)                                                                         \
    do {                                                                                  \
        __builtin_amdgcn_s_setprio(1);                                                    \
        _Pragma("unroll") for (int m_ = 0; m_ < 2; ++m_)                                  \
            _Pragma("unroll") for (int nf_ = 0; nf_ < 4; ++nf_)                           \
                _Pragma("unroll") for (int ks_ = 0; ks_ < 2; ++ks_)                       \
                    acc[2 * (q) + m_][nf_] = __builtin_amdgcn_mfma_f32_16x16x32_bf16(     \
                        bfr[nf_][ks_], af[m_][ks_], acc[2 * (q) + m_][nf_], 0, 0, 0);     \
        __builtin_amdgcn_s_setprio(0);                                                    \
    } while (0)

    f32x4 acc[8][4] = {};
    bf16x8 bfr[4][2];  // B frags of current K-tile (live 4 phases)
    bf16x8 af[2][2];   // A frags of current phase (transient)

    // ---- current / next K-pair state (wave-uniform) ----
    int mBc, nBc, mBn, nBn;
    DECODE(0, mBc, nBc);
    const unsigned short* gAc = A + (size_t)mBc * K;
    const unsigned short* gBc = Bt + (size_t)nBc * K;
    int kc = 0;
    mBn = mBc; nBn = nBc;
    const unsigned short* gAn = gAc;
    const unsigned short* gBn = gBc;
    int kn = 128;                    // NIp >= 2 guaranteed (K >= 256)
    int tj = 0;                      // tile ordinal of the NEXT pair

    // ---- prologue: T0 {A,B}->buf0, T1 {B}->buf1; leave T1-B (4 loads) in flight ----
    STG(gAc, sA, 0, 0, kc); STG(gAc, sA, 0, 1, kc);
    STG(gBc, sB, 0, 0, kc); STG(gBc, sB, 0, 1, kc);
    STG(gBc, sB, 1, 0, kc + 64); STG(gBc, sB, 1, 1, kc + 64);
    VMCNT(4);
    BAR();

    const int TP = cnt * (K >> 7);   // total K-pair iterations
    for (int P = 0; P < TP; ++P) {
        const bool more = (P + 1 < TP);
        // ---- p1: tile-pair 1st K-tile (buf0), quadrant 0 ----
        READ_B8(0); READ_A2(0, 0);
        STG(gAc, sA, 1, 0, kc + 64);
        BAR(); MFMA_Q(0); BAR();
        // ---- p2 ----
        READ_A2(0, 2);
        STG(gAc, sA, 1, 1, kc + 64);
        BAR(); MFMA_Q(1); BAR();
        // ---- p3 ----
        READ_A2(0, 4);
        if (more) STG(gBn, sB, 0, 0, kn);
        BAR(); MFMA_Q(2); BAR();
        // ---- p4: gate for 2nd K-tile ----
        READ_A2(0, 6);
        if (more) STG(gBn, sB, 0, 1, kn);
        BAR(); MFMA_Q(3);
        if (more) { VMCNT(4); } else { VMCNT(0); }
        BAR();
        // ---- p5: 2nd K-tile (buf1) ----
        READ_B8(1); READ_A2(1, 0);
        if (more) STG(gAn, sA, 0, 0, kn);
        BAR(); MFMA_Q(0); BAR();
        // ---- p6 ----
        READ_A2(1, 2);
        if (more) STG(gAn, sA, 0, 1, kn);
        BAR(); MFMA_Q(1); BAR();
        // ---- p7 ----
        READ_A2(1, 4);
        if (more) STG(gBn, sB, 1, 0, kn + 64);
        BAR(); MFMA_Q(2); BAR();
        // ---- p8: gate for next pair ----
        READ_A2(1, 6);
        if (more) STG(gBn, sB, 1, 1, kn + 64);
        BAR(); MFMA_Q(3);
        if (more) VMCNT(4);
        BAR();

        // ---- tile boundary: epilogue (C^T frags -> vector stores along n) ----
        if (kc + 128 == K) {
#pragma unroll
            for (int mf = 0; mf < 8; ++mf) {
                const int rowg = mBc + wm * 128 + mf * 16 + cl;
                const size_t rb = (size_t)rowg * N;
#pragma unroll
                for (int nf = 0; nf < 4; ++nf) {
                    const int colg = nBc + wn * 64 + nf * 16 + quad * 4;
                    const float4 bv = *(const float4*)(bias + colg);
                    const f32x4 a = acc[mf][nf];
                    const size_t idx = rb + colg;
                    if constexpr (EPI == 0) {
                        u16x4 o;
                        o[0] = f2bf(a[0] + bv.x); o[1] = f2bf(a[1] + bv.y);
                        o[2] = f2bf(a[2] + bv.z); o[3] = f2bf(a[3] + bv.w);
                        *(u16x4*)((unsigned short*)outp + idx) = o;
                    } else if constexpr (EPI == 1) {
                        const float4 rv = *(const float4*)(resid + idx);
                        float4 o;
                        o.x = a[0] + bv.x + rv.x; o.y = a[1] + bv.y + rv.y;
                        o.z = a[2] + bv.z + rv.z; o.w = a[3] + bv.w + rv.w;
                        *(float4*)((float*)outp + idx) = o;
                    } else {
                        u16x4 o;
                        o[0] = f2bf(fast_gelu(a[0] + bv.x));
                        o[1] = f2bf(fast_gelu(a[1] + bv.y));
                        o[2] = f2bf(fast_gelu(a[2] + bv.z));
                        o[3] = f2bf(fast_gelu(a[3] + bv.w));
                        *(u16x4*)((unsigned short*)outp + idx) = o;
                    }
                }
            }
            const f32x4 z = {0.f, 0.f, 0.f, 0.f};
#pragma unroll
            for (int mf = 0; mf < 8; ++mf)
#pragma unroll
                for (int nf = 0; nf < 4; ++nf) acc[mf][nf] = z;
        }
        // ---- advance cur <- next; next += 128 (wrap -> next tile) ----
        kc = kn; gAc = gAn; gBc = gBn; mBc = mBn; nBc = nBn;
        kn += 128;
        if (kn >= K) {
            kn = 0;
            ++tj;
            if (tj < cnt) {
                DECODE(tj, mBn, nBn);
                gAn = A + (size_t)mBn * K;
                gBn = Bt + (size_t)nBn * K;
            }
        }
    }
#undef STG
#undef READ_B8
#undef READ_A2
#undef MFMA_Q
#undef DECODE
}

// ---------------- MFMA flash attention, 128 q-rows/block, S^T softmax ----------------
// (unchanged, verified)
__global__ __launch_bounds__(256) void attn_mfma(const unsigned short* __restrict__ qkv,
                                                 unsigned short* __restrict__ ctx) {
    __shared__ __align__(16) unsigned short Ks[64 * 72];
    __shared__ __align__(16) unsigned int Vt[64 * 36];
    __shared__ __align__(16) unsigned short Ps[128 * 72];

    const int bh = blockIdx.x;
    const int qt = blockIdx.y;
    const int b = bh >> 4;
    const int h = bh & 15;
    const int t = threadIdx.x;
    const int w = t >> 6;
    const int lane = t & 63;
    const int quad = lane >> 4;
    const int cl = lane & 15;
    const size_t tok0 = (size_t)b * 1024;
    const int qrow0 = qt * 128 + w * 32;

    // Q fragments: operand [idx=cl][k=quad*8 + ks*32] (A/B identical layout)
    bf16x8 aq[2][2];
#pragma unroll
    for (int sub = 0; sub < 2; ++sub) {
        const unsigned short* qp =
            qkv + (tok0 + qrow0 + sub * 16 + cl) * 3072 + h * 64 + quad * 8;
        aq[sub][0] = *(const bf16x8*)(qp);
        aq[sub][1] = *(const bf16x8*)(qp + 32);
    }

    const bf16x8 vones = {0x3F80, 0x3F80, 0x3F80, 0x3F80, 0x3F80, 0x3F80, 0x3F80, 0x3F80};

    // staging indices
    const int r0 = t >> 2;         // K row 0..63
    const int c16 = (t & 3) * 16;  // K col chunk
    const int kp = t >> 3;         // V key-pair 0..31
    const int dc = t & 7;          // V d-chunk (8 d's)

    f32x4 acc[2][5] = {};          // [sub][j]; j=4 is the l-column (ones B-frag)
    float m_r[2] = {-3.0e38f, -3.0e38f};   // running max for q=cl, per sub

    for (int kt = 0; kt < 16; ++kt) {
        // ---- stage K [key][d] and V^T [d][key-pair dword] ----
        {
            const unsigned short* kg =
                qkv + (tok0 + kt * 64 + r0) * 3072 + 1024 + h * 64 + c16;
            *(int4*)(Ks + r0 * 72 + c16) = *(const int4*)(kg);
            *(int4*)(Ks + r0 * 72 + c16 + 8) = *(const int4*)(kg + 8);

            const unsigned short* vg =
                qkv + (tok0 + kt * 64 + 2 * kp) * 3072 + 2048 + h * 64 + dc * 8;
            u16x8 v0 = *(const u16x8*)(vg);
            u16x8 v1 = *(const u16x8*)(vg + 3072);
            const int g = kp >> 2, wd = kp & 3;
#pragma unroll
            for (int j = 0; j < 8; ++j) {
                const int d = dc * 8 + j;
                Vt[d * 36 + (((g ^ (d >> 3)) << 2) | wd)] =
                    ((unsigned int)v1[j] << 16) | (unsigned int)v0[j];
            }
        }
        __syncthreads();

#pragma unroll
        for (int sub = 0; sub < 2; ++sub) {
            // ---- S^T = K·Q^T (operand-swapped MFMA) ----
            f32x4 sc[4] = {};
#pragma unroll
            for (int i = 0; i < 4; ++i) {
                const int rb = i * 16 + cl;
#pragma unroll
                for (int ks = 0; ks < 2; ++ks) {
                    bf16x8 bk = *(const bf16x8*)(Ks + rb * 72 + quad * 8 + ks * 32);
                    sc[i] = __builtin_amdgcn_mfma_f32_16x16x32_bf16(bk, aq[sub][ks], sc[i],
                                                                    0, 0, 0);
                }
            }
            // ---- softmax for q = cl: all 64 key-scores live in this lane + 3 quad-mates
            float mx0 = fmaxf(fmaxf(sc[0][0], sc[0][1]), fmaxf(sc[0][2], sc[0][3]));
            float mx1 = fmaxf(fmaxf(sc[1][0], sc[1][1]), fmaxf(sc[1][2], sc[1][3]));
            float mx2 = fmaxf(fmaxf(sc[2][0], sc[2][1]), fmaxf(sc[2][2], sc[2][3]));
            float mx3 = fmaxf(fmaxf(sc[3][0], sc[3][1]), fmaxf(sc[3][2], sc[3][3]));
            float rmax = fmaxf(fmaxf(mx0, mx1), fmaxf(mx2, mx3));
            rmax = fmaxf(rmax, __shfl_xor(rmax, 16));
            rmax = fmaxf(rmax, __shfl_xor(rmax, 32));
            const float mnew = fmaxf(m_r[sub], rmax * 0.125f);
            const float alpha = __expf(m_r[sub] - mnew);
            m_r[sub] = mnew;
            // alpha for this lane's O rows (q = quad*4+rr) from lane cl'=quad*4+rr
            float al[4];
#pragma unroll
            for (int rr = 0; rr < 4; ++rr) al[rr] = __shfl(alpha, quad * 4 + rr, 16);
#pragma unroll
            for (int j = 0; j < 5; ++j)
#pragma unroll
                for (int rr = 0; rr < 4; ++rr) acc[sub][j][rr] *= al[rr];
            // P = exp(S - m) for 16 consecutive-key values; pack & store as 2 dwords/i
            const unsigned short* pr = Ps + (w * 32 + sub * 16 + cl) * 72;
#pragma unroll
            for (int i = 0; i < 4; ++i) {
                const float p0 = __expf(fmaf(sc[i][0], 0.125f, -mnew));
                const float p1 = __expf(fmaf(sc[i][1], 0.125f, -mnew));
                const float p2 = __expf(fmaf(sc[i][2], 0.125f, -mnew));
                const float p3 = __expf(fmaf(sc[i][3], 0.125f, -mnew));
                uint2 pk;
                pk.x = pkbf_trunc(p0, p1);
                pk.y = pkbf_trunc(p2, p3);
                *(uint2*)(pr + i * 16 + quad * 4) = pk;
            }
        }

        // ---- PV (+ l via ones-column) ----
#pragma unroll
        for (int ks = 0; ks < 2; ++ks) {
            bf16x8 bv[4];
#pragma unroll
            for (int j = 0; j < 4; ++j) {
                const int d = j * 16 + cl;
                bv[j] = *(const bf16x8*)(Vt + d * 36 + (((quad + 4 * ks) ^ (d >> 3)) << 2));
            }
#pragma unroll
            for (int sub = 0; sub < 2; ++sub) {
                bf16x8 ap =
                    *(const bf16x8*)(Ps + (w * 32 + sub * 16 + cl) * 72 + quad * 8 + ks * 32);
#pragma unroll
                for (int j = 0; j < 4; ++j)
                    acc[sub][j] =
                        __builtin_amdgcn_mfma_f32_16x16x32_bf16(ap, bv[j], acc[sub][j], 0, 0, 0);
                acc[sub][4] =
                    __builtin_amdgcn_mfma_f32_16x16x32_bf16(ap, vones, acc[sub][4], 0, 0, 0);
            }
        }
        __syncthreads();  // Ks/Vt reads done before next staging
    }

    // ---- epilogue: O = acc / l (l = ones-column), bf16 store ----
#pragma unroll
    for (int sub = 0; sub < 2; ++sub)
#pragma unroll
        for (int rr = 0; rr < 4; ++rr) {
            const float inv = 1.0f / acc[sub][4][rr];
            const size_t tok = tok0 + qt * 128 + w * 32 + sub * 16 + quad * 4 + rr;
#pragma unroll
            for (int j = 0; j < 4; ++j)
                ctx[tok * 1024 + h * 64 + j * 16 + cl] = f2bf(acc[sub][j][rr] * inv);
        }
}

extern "C" void kernel_launch(void* const* d_in, const int* in_sizes, int n_in,
                              void* d_out, int out_size, void* d_ws, size_t ws_size,
                              hipStream_t stream) {
    const float* x    = (const float*)d_in[0];
    const float* wqkv = (const float*)d_in[1];
    const float* bqkv = (const float*)d_in[2];
    const float* wo   = (const float*)d_in[3];
    const float* bo   = (const float*)d_in[4];
    const float* w1   = (const float*)d_in[5];
    const float* b1   = (const float*)d_in[6];
    const float* w2   = (const float*)d_in[7];
    const float* b2   = (const float*)d_in[8];
    const float* n1w  = (const float*)d_in[9];
    const float* n1b  = (const float*)d_in[10];
    const float* n2w  = (const float*)d_in[11];
    const float* n2b  = (const float*)d_in[12];
    float* out = (float*)d_out;   // also serves as x1 (residual stream after attention)

    char* ws = (char*)d_ws;
    unsigned short* wqkv_b = (unsigned short*)(ws);
    unsigned short* wo_b   = (unsigned short*)(ws + 6291456);
    unsigned short* w1_b   = (unsigned short*)(ws + 8388608);
    unsigned short* w2_b   = (unsigned short*)(ws + 16777216);
    unsigned short* r1     = (unsigned short*)(ws + 25165824);  // xn -> ctx -> xn2
    unsigned short* r2     = (unsigned short*)(ws + 58720256);  // qkv -> h

    unsigned short* xn_b  = r1;
    unsigned short* ctx_b = r1;
    unsigned short* xn2_b = r1;
    unsigned short* qkv_b = r2;
    unsigned short* h_b   = r2;

    cvt_kernel<<<3072, 256, 0, stream>>>(wqkv, wqkv_b, 786432);
    cvt_kernel<<<1024, 256, 0, stream>>>(wo, wo_b, 262144);
    cvt_kernel<<<4096, 256, 0, stream>>>(w1, w1_b, 1048576);
    cvt_kernel<<<4096, 256, 0, stream>>>(w2, w2_b, 1048576);

    ln_kernel<<<16384, 256, 0, stream>>>(x, n1w, n1b, xn_b);
    // QKV: GY=64, GX=12 -> NC=3, MC=32; nt=768, 256 blocks x 3
    gemm_bt<0><<<256, 512, 0, stream>>>(xn_b, wqkv_b, bqkv, nullptr, qkv_b,
                                        16384, 3072, 1024, 3, 3, 32);
    attn_mfma<<<dim3(256, 8), 256, 0, stream>>>(qkv_b, ctx_b);
    // proj: GY=64, GX=4 -> NC=1, MC=32; nt=256, 256 blocks x 1
    gemm_bt<1><<<256, 512, 0, stream>>>(ctx_b, wo_b, bo, x, out,
                                        16384, 1024, 1024, 1, 1, 32);
    ln_kernel<<<16384, 256, 0, stream>>>(out, n2w, n2b, xn2_b);

    // FFN: single pass if h (128 MB @ region2) fits, else 2 row-chunks of 8192 tokens.
    // ws_size is constant across calls -> branch is graph-capture safe.
    if (ws_size >= 192937984ULL) {
        // lin1: GY=64, GX=16 -> NC=4, MC=32; nt=1024, 256 blocks x 4
        gemm_bt<2><<<256, 512, 0, stream>>>(xn2_b, w1_b, b1, nullptr, h_b,
                                            16384, 4096, 1024, 4, 4, 32);
        // lin2: GY=64, GX=4 -> NC=1, MC=32; nt=256, 256 blocks x 1
        gemm_bt<1><<<256, 512, 0, stream>>>(h_b, w2_b, b2, out, out,
                                            16384, 1024, 4096, 1, 1, 32);
    } else {
        for (int c = 0; c < 2; ++c) {
            const size_t row0 = (size_t)c * 8192;
            // lin1 chunk: GY=32 -> MC=16, NC=4; nt=512, 256 blocks x 2
            gemm_bt<2><<<256, 512, 0, stream>>>(xn2_b + row0 * 1024, w1_b, b1,
                                                nullptr, h_b, 8192, 4096, 1024, 2, 4, 16);
            // lin2 chunk: GY=32 -> MC=16, NC=1; nt=128, 128 blocks x 1
            gemm_bt<1><<<128, 512, 0, stream>>>(h_b, w2_b, b2, out + row0 * 1024,
                                                out + row0 * 1024, 8192, 1024, 4096,
                                                1, 1, 16);
        }
    }
}

// Round 5
// 855.632 us; speedup vs baseline: 1.0199x; 1.0199x over previous
//
#include <hip/hip_runtime.h>

// B=16,S=1024,E=1024,F=4096,H=16,D=64. N = B*S = 16384 tokens.
// Pipeline: LN1 -> QKV gemm(bf16 MFMA)+bias -> MFMA flash attn (S^T softmax) ->
//           proj gemm+bias+resid -> d_out -> LN2 -> lin1 gemm+bias+GELU ->
//           lin2 gemm+bias+resid(in-place d_out). FFN single-pass if ws allows, else 2-chunk.
//
// GEMM engine: PERSISTENT 256x256 tile, BK=64, 512 thr (8 waves 2Mx4N), double-buffered
// 128 KB LDS, 8-phase counted-vmcnt schedule (T3+T4+T5), 2D XCD chunking, C^T epilogue.
// R5: SINGLE barrier per phase ({READ || STG -> BAR -> MFMA}); post-MFMA barriers kept
// only at the p4/p8 vmcnt gates. Lets phase p+1's LDS-read burst overlap phase p's MFMA
// tail across waves (LDS unit ~700 cyc/phase and MFMA pipe ~620 cyc/phase were fully
// serialized by the two-barrier layout). WAR audit: every overwritten LDS region's last
// readers complete their ds_reads at their own lgkm-wait (before their MFMA), which
// precedes >=1 barrier before the overwriting STG is issued. vmcnt ledger unchanged.
//
// Workspace plan:
//   0          wqkv_b  bf16 3072x1024   (6 MB)
//   6291456    wo_b    bf16 1024x1024   (2 MB)
//   8388608    w1_b    bf16 4096x1024   (8 MB)
//   16777216   w2_b    bf16 1024x4096   (8 MB)
//   25165824   region1 (32 MB): xn_b -> ctx_b -> xn2_b
//   58720256   region2: qkv_b (96 MB) -> h (128 MB single-pass if ws_size>=184MiB,
//                                            else 64 MB chunks, 2-pass)
// x1 (fp32) lives in d_out; lin2 updates d_out in place (same-thread R->W).

typedef __attribute__((ext_vector_type(8))) short bf16x8;
typedef __attribute__((ext_vector_type(4))) float f32x4;
typedef __attribute__((ext_vector_type(8))) unsigned short u16x8;
typedef __attribute__((ext_vector_type(4))) unsigned short u16x4;

__device__ __forceinline__ float bf2f(unsigned short u) {
    return __uint_as_float(((unsigned int)u) << 16);
}
__device__ __forceinline__ unsigned short f2bf(float f) {
    unsigned int u = __float_as_uint(f);
    u += 0x7fffu + ((u >> 16) & 1u);   // RNE
    return (unsigned short)(u >> 16);
}
// pack two positive f32 into bf16x2 dword by truncation (P in [0,1])
__device__ __forceinline__ unsigned int pkbf_trunc(float a, float b) {
    return (__float_as_uint(a) >> 16) | (__float_as_uint(b) & 0xffff0000u);
}

// GELU with A&S 7.1.26 erf (|err| <= 1.5e-7)
__device__ __forceinline__ float fast_gelu(float v) {
    const float x = v * 0.70710678118654752f;
    const float ax = fabsf(x);
    const float t = __builtin_amdgcn_rcpf(fmaf(0.3275911f, ax, 1.0f));
    float p = fmaf(1.061405429f, t, -1.453152027f);
    p = fmaf(p, t, 1.421413741f);
    p = fmaf(p, t, -0.284496736f);
    p = fmaf(p, t, 0.254829592f);
    p = p * t;
    const float e = __expf(-x * x);
    float erfv = fmaf(-p, e, 1.0f);
    erfv = (x < 0.0f) ? -erfv : erfv;
    return 0.5f * v * (1.0f + erfv);
}

// async global->LDS, 16 B per lane; LDS dest is wave-uniform base + lane*16
__device__ __forceinline__ void gload_lds16(const unsigned short* g, unsigned short* l) {
    __builtin_amdgcn_global_load_lds(
        (const __attribute__((address_space(1))) unsigned int*)g,
        (__attribute__((address_space(3))) unsigned int*)l, 16, 0, 0);
}

// compiler memory fence (free) + raw barrier: does NOT drain vmcnt (unlike __syncthreads)
#define FENCE() asm volatile("" ::: "memory")
#define BAR()                         \
    do {                              \
        FENCE();                      \
        __builtin_amdgcn_s_barrier(); \
        FENCE();                      \
    } while (0)
#define VMCNT(n)                                               \
    do {                                                       \
        asm volatile("s_waitcnt vmcnt(" #n ")" ::: "memory");  \
        __builtin_amdgcn_sched_barrier(0);                     \
    } while (0)

// ---------------- fp32 -> bf16 weight conversion ----------------
__global__ __launch_bounds__(256) void cvt_kernel(const float* __restrict__ in,
                                                  unsigned short* __restrict__ out, int n4) {
    int i = blockIdx.x * 256 + threadIdx.x;
    if (i >= n4) return;
    float4 v = ((const float4*)in)[i];
    u16x4 o;
    o[0] = f2bf(v.x); o[1] = f2bf(v.y); o[2] = f2bf(v.z); o[3] = f2bf(v.w);
    ((u16x4*)out)[i] = o;
}

// ---------------- LayerNorm (E=1024), fp32 in -> bf16 out ----------------
__global__ __launch_bounds__(256) void ln_kernel(const float* __restrict__ x,
                                                 const float* __restrict__ w,
                                                 const float* __restrict__ b,
                                                 unsigned short* __restrict__ out) {
    const int row = blockIdx.x;
    const int t = threadIdx.x;
    const float* xr = x + (size_t)row * 1024;
    float4 v = *(const float4*)(xr + t * 4);
    float s = v.x + v.y + v.z + v.w;
    float sq = v.x * v.x + v.y * v.y + v.z * v.z + v.w * v.w;
#pragma unroll
    for (int off = 32; off > 0; off >>= 1) {
        s += __shfl_xor(s, off);
        sq += __shfl_xor(sq, off);
    }
    __shared__ float rs_[4], rq_[4];
    if ((t & 63) == 0) { rs_[t >> 6] = s; rq_[t >> 6] = sq; }
    __syncthreads();
    s = rs_[0] + rs_[1] + rs_[2] + rs_[3];
    sq = rq_[0] + rq_[1] + rq_[2] + rq_[3];
    const float mu = s * (1.0f / 1024.0f);
    const float var = sq * (1.0f / 1024.0f) - mu * mu;
    const float rstd = rsqrtf(var + 1e-5f);
    const int c = t * 4;
    float4 wv = *(const float4*)(w + c);
    float4 bv = *(const float4*)(b + c);
    u16x4 o;
    o[0] = f2bf((v.x - mu) * rstd * wv.x + bv.x);
    o[1] = f2bf((v.y - mu) * rstd * wv.y + bv.y);
    o[2] = f2bf((v.z - mu) * rstd * wv.z + bv.z);
    o[3] = f2bf((v.w - mu) * rstd * wv.w + bv.w);
    *(u16x4*)(out + (size_t)row * 1024 + c) = o;
}

// ---------------- persistent bf16 MFMA GEMM: C[M,N] = A[M,K] @ Bt[N,K]^T ----------------
// Per phase: {ds_read 4-12 x b128 (base+imm) || issue 2x global_load_lds -> s_barrier ->
//             (lgkm-wait) setprio(1) 16x mfma(SWAPPED -> C^T frags) setprio(0)}
// Post-MFMA barrier ONLY after the p4/p8 vmcnt(4) gates (single-barrier phases).
// Stage order (per iteration P over pair {2P,2P+1}):
//   p1/p2: A of pair's 2nd K-tile (buf1); p3/p4: B of next pair 1st (buf0);
//   p5/p6: A of next pair 1st (buf0);     p7/p8: B of next pair 2nd (buf1).
// Gates: p4 VMCNT(4) drains buf1{A,B} (leaves p3/p4 in flight); p8 VMCNT(4) drains
// buf0{A,B} (leaves p7/p8 in flight). Both landed region-complete before first read.
// C^T fragment layout: thread(w,quad,cl): m = wm*128+mf*16+cl ; n = wn*64+nf*16+quad*4+rr
// (rr consecutive in n -> 8B/16B vector stores).
// Tile order: XCD x = g&7 as (xm=x>>2, xn=x&3); XCD owns MC m-tiles x NC n-tiles,
// n-fastest within. l = (g>>3) + tj*(NB/8); mi = l/NC, ni = l%NC.
// EPI: 0 bias->bf16 ; 1 bias+resid->f32 ; 2 bias+GELU->bf16
// Requires M%256==0, N%256==0, K%128==0, K>=256, GY%2==0, (N/256)%4==0,
// nt%gridDim.x==0, gridDim.x%8==0, MC=GY/2, NC=(N/256)/4.
template <int EPI>
__global__ __launch_bounds__(512, 2) void gemm_bt(const unsigned short* __restrict__ A,
                                                  const unsigned short* __restrict__ Bt,
                                                  const float* __restrict__ bias,
                                                  const float* __restrict__ resid,
                                                  void* __restrict__ outp,
                                                  int M, int N, int K, int cnt,
                                                  int NC, int MC) {
    __shared__ __align__(16) unsigned short sA[2][256 * 64];
    __shared__ __align__(16) unsigned short sB[2][256 * 64];
    const int t = threadIdx.x;
    const int lane = t & 63;
    const int w = t >> 6;            // 0..7
    const int wm = w >> 2;           // 0..1  (wave M index)
    const int wn = w & 3;            // 0..3  (wave N index)
    const int quad = lane >> 4;
    const int cl = lane & 15;

    const int NB = gridDim.x;
    const int g = blockIdx.x;
    const int lpb = NB >> 3;         // per-XCD block count (l stride per tile step)
    const int xm = (g >> 2) & 1;     // XCD m-row   (x = g&7 -> xm = bit2, xn = bits0..1)
    const int xn = g & 3;            // XCD n-col
    const int l0 = g >> 3;

    // decode tile ordinal tj -> (mB, nB)
#define DECODE(tjv, mB, nB)                                  \
    do {                                                     \
        const int l_ = l0 + (tjv) * lpb;                     \
        const int mi_ = l_ / NC;                             \
        const int ni_ = l_ - mi_ * NC;                       \
        (mB) = (xm * MC + mi_) << 8;                         \
        (nB) = (xn * NC + ni_) << 8;                         \
    } while (0)

    // ---- precomputed per-thread LDS read bases (byte pointers; reads = base+imm) ----
    const int swz0 = (quad ^ (cl & 7)) * 16;           // ks=0 chunk byte offset
    const int swz1 = ((quad + 4) ^ (cl & 7)) * 16;     // ks=1 chunk byte offset
    const char* aB0 = (const char*)sA + (wm * 128 + cl) * 128 + swz0;
    const char* aB1 = (const char*)sA + (wm * 128 + cl) * 128 + swz1;
    const char* bB0 = (const char*)sB + (wn * 64 + cl) * 128 + swz0;
    const char* bB1 = (const char*)sB + (wn * 64 + cl) * 128 + swz1;

    // ---- precomputed per-thread staging offset (elements): (w*16 + rl)*K + ch ----
    const int rl = lane >> 3;
    const size_t o8 = (size_t)8 * K;
    const size_t o128 = (size_t)128 * K;
    const size_t thr = (size_t)(w * 16 + rl) * K + (size_t)(((lane & 7) ^ rl) * 8);

#define STG(gp, sbuf, buf, hf, k0)                                                        \
    do {                                                                                  \
        gload_lds16((gp) + (k0) + thr + (hf) * o128,                                      \
                    &sbuf[buf][((hf) * 128 + w * 16) * 64]);                              \
        gload_lds16((gp) + (k0) + thr + (hf) * o128 + o8,                                 \
                    &sbuf[buf][((hf) * 128 + w * 16 + 8) * 64]);                          \
    } while (0)
#define READ_B8(buf)                                                                      \
    do {                                                                                  \
        _Pragma("unroll") for (int nf_ = 0; nf_ < 4; ++nf_) {                             \
            bfr[nf_][0] = *(const bf16x8*)(bB0 + (buf) * 32768 + nf_ * 2048);             \
            bfr[nf_][1] = *(const bf16x8*)(bB1 + (buf) * 32768 + nf_ * 2048);             \
        }                                                                                 \
    } while (0)
#define READ_A2(buf, mfb)                                                                 \
    do {                                                                                  \
        af[0][0] = *(const bf16x8*)(aB0 + (buf) * 32768 + (mfb) * 2048);                  \
        af[0][1] = *(const bf16x8*)(aB1 + (buf) * 32768 + (mfb) * 2048);                  \
        af[1][0] = *(const bf16x8*)(aB0 + (buf) * 32768 + ((mfb) + 1) * 2048);            \
        af[1][1] = *(const bf16x8*)(aB1 + (buf) * 32768 + ((mfb) + 1) * 2048);            \
    } while (0)
// SWAPPED operands: D^T fragments (A/B frag layouts identical for 16x16x32)
#define MFMA_Q(q)                                                                         \
    do {                                                                                  \
        __builtin_amdgcn_s_setprio(1);                                                    \
        _Pragma("unroll") for (int m_ = 0; m_ < 2; ++m_)                                  \
            _Pragma("unroll") for (int nf_ = 0; nf_ < 4; ++nf_)                           \
                _Pragma("unroll") for (int ks_ = 0; ks_ < 2; ++ks_)                       \
                    acc[2 * (q) + m_][nf_] = __builtin_amdgcn_mfma_f32_16x16x32_bf16(     \
                        bfr[nf_][ks_], af[m_][ks_], acc[2 * (q) + m_][nf_], 0, 0, 0);     \
        __builtin_amdgcn_s_setprio(0);                                                    \
    } while (0)

    f32x4 acc[8][4] = {};
    bf16x8 bfr[4][2];  // B frags of current K-tile (live 4 phases)
    bf16x8 af[2][2];   // A frags of current phase (transient)

    // ---- current / next K-pair state (wave-uniform) ----
    int mBc, nBc, mBn, nBn;
    DECODE(0, mBc, nBc);
    const unsigned short* gAc = A + (size_t)mBc * K;
    const unsigned short* gBc = Bt + (size_t)nBc * K;
    int kc = 0;
    mBn = mBc; nBn = nBc;
    const unsigned short* gAn = gAc;
    const unsigned short* gBn = gBc;
    int kn = 128;                    // NIp >= 2 guaranteed (K >= 256)
    int tj = 0;                      // tile ordinal of the NEXT pair

    // ---- prologue: T0 {A,B}->buf0, T1 {B}->buf1; leave T1-B (4 loads) in flight ----
    STG(gAc, sA, 0, 0, kc); STG(gAc, sA, 0, 1, kc);
    STG(gBc, sB, 0, 0, kc); STG(gBc, sB, 0, 1, kc);
    STG(gBc, sB, 1, 0, kc + 64); STG(gBc, sB, 1, 1, kc + 64);
    VMCNT(4);
    BAR();

    const int TP = cnt * (K >> 7);   // total K-pair iterations
    for (int P = 0; P < TP; ++P) {
        const bool more = (P + 1 < TP);
        // ---- p1: tile-pair 1st K-tile (buf0), quadrant 0 ----
        READ_B8(0); READ_A2(0, 0);
        STG(gAc, sA, 1, 0, kc + 64);
        BAR(); MFMA_Q(0);
        // ---- p2 ----
        READ_A2(0, 2);
        STG(gAc, sA, 1, 1, kc + 64);
        BAR(); MFMA_Q(1);
        // ---- p3 ----
        READ_A2(0, 4);
        if (more) STG(gBn, sB, 0, 0, kn);
        BAR(); MFMA_Q(2);
        // ---- p4: gate for 2nd K-tile ----
        READ_A2(0, 6);
        if (more) STG(gBn, sB, 0, 1, kn);
        BAR(); MFMA_Q(3);
        if (more) { VMCNT(4); } else { VMCNT(0); }
        BAR();
        // ---- p5: 2nd K-tile (buf1) ----
        READ_B8(1); READ_A2(1, 0);
        if (more) STG(gAn, sA, 0, 0, kn);
        BAR(); MFMA_Q(0);
        // ---- p6 ----
        READ_A2(1, 2);
        if (more) STG(gAn, sA, 0, 1, kn);
        BAR(); MFMA_Q(1);
        // ---- p7 ----
        READ_A2(1, 4);
        if (more) STG(gBn, sB, 1, 0, kn + 64);
        BAR(); MFMA_Q(2);
        // ---- p8: gate for next pair ----
        READ_A2(1, 6);
        if (more) STG(gBn, sB, 1, 1, kn + 64);
        BAR(); MFMA_Q(3);
        if (more) VMCNT(4);
        BAR();

        // ---- tile boundary: epilogue (C^T frags -> vector stores along n) ----
        if (kc + 128 == K) {
#pragma unroll
            for (int mf = 0; mf < 8; ++mf) {
                const int rowg = mBc + wm * 128 + mf * 16 + cl;
                const size_t rb = (size_t)rowg * N;
#pragma unroll
                for (int nf = 0; nf < 4; ++nf) {
                    const int colg = nBc + wn * 64 + nf * 16 + quad * 4;
                    const float4 bv = *(const float4*)(bias + colg);
                    const f32x4 a = acc[mf][nf];
                    const size_t idx = rb + colg;
                    if constexpr (EPI == 0) {
                        u16x4 o;
                        o[0] = f2bf(a[0] + bv.x); o[1] = f2bf(a[1] + bv.y);
                        o[2] = f2bf(a[2] + bv.z); o[3] = f2bf(a[3] + bv.w);
                        *(u16x4*)((unsigned short*)outp + idx) = o;
                    } else if constexpr (EPI == 1) {
                        const float4 rv = *(const float4*)(resid + idx);
                        float4 o;
                        o.x = a[0] + bv.x + rv.x; o.y = a[1] + bv.y + rv.y;
                        o.z = a[2] + bv.z + rv.z; o.w = a[3] + bv.w + rv.w;
                        *(float4*)((float*)outp + idx) = o;
                    } else {
                        u16x4 o;
                        o[0] = f2bf(fast_gelu(a[0] + bv.x));
                        o[1] = f2bf(fast_gelu(a[1] + bv.y));
                        o[2] = f2bf(fast_gelu(a[2] + bv.z));
                        o[3] = f2bf(fast_gelu(a[3] + bv.w));
                        *(u16x4*)((unsigned short*)outp + idx) = o;
                    }
                }
            }
            const f32x4 z = {0.f, 0.f, 0.f, 0.f};
#pragma unroll
            for (int mf = 0; mf < 8; ++mf)
#pragma unroll
                for (int nf = 0; nf < 4; ++nf) acc[mf][nf] = z;
        }
        // ---- advance cur <- next; next += 128 (wrap -> next tile) ----
        kc = kn; gAc = gAn; gBc = gBn; mBc = mBn; nBc = nBn;
        kn += 128;
        if (kn >= K) {
            kn = 0;
            ++tj;
            if (tj < cnt) {
                DECODE(tj, mBn, nBn);
                gAn = A + (size_t)mBn * K;
                gBn = Bt + (size_t)nBn * K;
            }
        }
    }
#undef STG
#undef READ_B8
#undef READ_A2
#undef MFMA_Q
#undef DECODE
}

// ---------------- MFMA flash attention, 128 q-rows/block, S^T softmax ----------------
// (unchanged, verified)
__global__ __launch_bounds__(256) void attn_mfma(const unsigned short* __restrict__ qkv,
                                                 unsigned short* __restrict__ ctx) {
    __shared__ __align__(16) unsigned short Ks[64 * 72];
    __shared__ __align__(16) unsigned int Vt[64 * 36];
    __shared__ __align__(16) unsigned short Ps[128 * 72];

    const int bh = blockIdx.x;
    const int qt = blockIdx.y;
    const int b = bh >> 4;
    const int h = bh & 15;
    const int t = threadIdx.x;
    const int w = t >> 6;
    const int lane = t & 63;
    const int quad = lane >> 4;
    const int cl = lane & 15;
    const size_t tok0 = (size_t)b * 1024;
    const int qrow0 = qt * 128 + w * 32;

    // Q fragments: operand [idx=cl][k=quad*8 + ks*32] (A/B identical layout)
    bf16x8 aq[2][2];
#pragma unroll
    for (int sub = 0; sub < 2; ++sub) {
        const unsigned short* qp =
            qkv + (tok0 + qrow0 + sub * 16 + cl) * 3072 + h * 64 + quad * 8;
        aq[sub][0] = *(const bf16x8*)(qp);
        aq[sub][1] = *(const bf16x8*)(qp + 32);
    }

    const bf16x8 vones = {0x3F80, 0x3F80, 0x3F80, 0x3F80, 0x3F80, 0x3F80, 0x3F80, 0x3F80};

    // staging indices
    const int r0 = t >> 2;         // K row 0..63
    const int c16 = (t & 3) * 16;  // K col chunk
    const int kp = t >> 3;         // V key-pair 0..31
    const int dc = t & 7;          // V d-chunk (8 d's)

    f32x4 acc[2][5] = {};          // [sub][j]; j=4 is the l-column (ones B-frag)
    float m_r[2] = {-3.0e38f, -3.0e38f};   // running max for q=cl, per sub

    for (int kt = 0; kt < 16; ++kt) {
        // ---- stage K [key][d] and V^T [d][key-pair dword] ----
        {
            const unsigned short* kg =
                qkv + (tok0 + kt * 64 + r0) * 3072 + 1024 + h * 64 + c16;
            *(int4*)(Ks + r0 * 72 + c16) = *(const int4*)(kg);
            *(int4*)(Ks + r0 * 72 + c16 + 8) = *(const int4*)(kg + 8);

            const unsigned short* vg =
                qkv + (tok0 + kt * 64 + 2 * kp) * 3072 + 2048 + h * 64 + dc * 8;
            u16x8 v0 = *(const u16x8*)(vg);
            u16x8 v1 = *(const u16x8*)(vg + 3072);
            const int g = kp >> 2, wd = kp & 3;
#pragma unroll
            for (int j = 0; j < 8; ++j) {
                const int d = dc * 8 + j;
                Vt[d * 36 + (((g ^ (d >> 3)) << 2) | wd)] =
                    ((unsigned int)v1[j] << 16) | (unsigned int)v0[j];
            }
        }
        __syncthreads();

#pragma unroll
        for (int sub = 0; sub < 2; ++sub) {
            // ---- S^T = K·Q^T (operand-swapped MFMA) ----
            f32x4 sc[4] = {};
#pragma unroll
            for (int i = 0; i < 4; ++i) {
                const int rb = i * 16 + cl;
#pragma unroll
                for (int ks = 0; ks < 2; ++ks) {
                    bf16x8 bk = *(const bf16x8*)(Ks + rb * 72 + quad * 8 + ks * 32);
                    sc[i] = __builtin_amdgcn_mfma_f32_16x16x32_bf16(bk, aq[sub][ks], sc[i],
                                                                    0, 0, 0);
                }
            }
            // ---- softmax for q = cl: all 64 key-scores live in this lane + 3 quad-mates
            float mx0 = fmaxf(fmaxf(sc[0][0], sc[0][1]), fmaxf(sc[0][2], sc[0][3]));
            float mx1 = fmaxf(fmaxf(sc[1][0], sc[1][1]), fmaxf(sc[1][2], sc[1][3]));
            float mx2 = fmaxf(fmaxf(sc[2][0], sc[2][1]), fmaxf(sc[2][2], sc[2][3]));
            float mx3 = fmaxf(fmaxf(sc[3][0], sc[3][1]), fmaxf(sc[3][2], sc[3][3]));
            float rmax = fmaxf(fmaxf(mx0, mx1), fmaxf(mx2, mx3));
            rmax = fmaxf(rmax, __shfl_xor(rmax, 16));
            rmax = fmaxf(rmax, __shfl_xor(rmax, 32));
            const float mnew = fmaxf(m_r[sub], rmax * 0.125f);
            const float alpha = __expf(m_r[sub] - mnew);
            m_r[sub] = mnew;
            // alpha for this lane's O rows (q = quad*4+rr) from lane cl'=quad*4+rr
            float al[4];
#pragma unroll
            for (int rr = 0; rr < 4; ++rr) al[rr] = __shfl(alpha, quad * 4 + rr, 16);
#pragma unroll
            for (int j = 0; j < 5; ++j)
#pragma unroll
                for (int rr = 0; rr < 4; ++rr) acc[sub][j][rr] *= al[rr];
            // P = exp(S - m) for 16 consecutive-key values; pack & store as 2 dwords/i
            const unsigned short* pr = Ps + (w * 32 + sub * 16 + cl) * 72;
#pragma unroll
            for (int i = 0; i < 4; ++i) {
                const float p0 = __expf(fmaf(sc[i][0], 0.125f, -mnew));
                const float p1 = __expf(fmaf(sc[i][1], 0.125f, -mnew));
                const float p2 = __expf(fmaf(sc[i][2], 0.125f, -mnew));
                const float p3 = __expf(fmaf(sc[i][3], 0.125f, -mnew));
                uint2 pk;
                pk.x = pkbf_trunc(p0, p1);
                pk.y = pkbf_trunc(p2, p3);
                *(uint2*)(pr + i * 16 + quad * 4) = pk;
            }
        }

        // ---- PV (+ l via ones-column) ----
#pragma unroll
        for (int ks = 0; ks < 2; ++ks) {
            bf16x8 bv[4];
#pragma unroll
            for (int j = 0; j < 4; ++j) {
                const int d = j * 16 + cl;
                bv[j] = *(const bf16x8*)(Vt + d * 36 + (((quad + 4 * ks) ^ (d >> 3)) << 2));
            }
#pragma unroll
            for (int sub = 0; sub < 2; ++sub) {
                bf16x8 ap =
                    *(const bf16x8*)(Ps + (w * 32 + sub * 16 + cl) * 72 + quad * 8 + ks * 32);
#pragma unroll
                for (int j = 0; j < 4; ++j)
                    acc[sub][j] =
                        __builtin_amdgcn_mfma_f32_16x16x32_bf16(ap, bv[j], acc[sub][j], 0, 0, 0);
                acc[sub][4] =
                    __builtin_amdgcn_mfma_f32_16x16x32_bf16(ap, vones, acc[sub][4], 0, 0, 0);
            }
        }
        __syncthreads();  // Ks/Vt reads done before next staging
    }

    // ---- epilogue: O = acc / l (l = ones-column), bf16 store ----
#pragma unroll
    for (int sub = 0; sub < 2; ++sub)
#pragma unroll
        for (int rr = 0; rr < 4; ++rr) {
            const float inv = 1.0f / acc[sub][4][rr];
            const size_t tok = tok0 + qt * 128 + w * 32 + sub * 16 + quad * 4 + rr;
#pragma unroll
            for (int j = 0; j < 4; ++j)
                ctx[tok * 1024 + h * 64 + j * 16 + cl] = f2bf(acc[sub][j][rr] * inv);
        }
}

extern "C" void kernel_launch(void* const* d_in, const int* in_sizes, int n_in,
                              void* d_out, int out_size, void* d_ws, size_t ws_size,
                              hipStream_t stream) {
    const float* x    = (const float*)d_in[0];
    const float* wqkv = (const float*)d_in[1];
    const float* bqkv = (const float*)d_in[2];
    const float* wo   = (const float*)d_in[3];
    const float* bo   = (const float*)d_in[4];
    const float* w1   = (const float*)d_in[5];
    const float* b1   = (const float*)d_in[6];
    const float* w2   = (const float*)d_in[7];
    const float* b2   = (const float*)d_in[8];
    const float* n1w  = (const float*)d_in[9];
    const float* n1b  = (const float*)d_in[10];
    const float* n2w  = (const float*)d_in[11];
    const float* n2b  = (const float*)d_in[12];
    float* out = (float*)d_out;   // also serves as x1 (residual stream after attention)

    char* ws = (char*)d_ws;
    unsigned short* wqkv_b = (unsigned short*)(ws);
    unsigned short* wo_b   = (unsigned short*)(ws + 6291456);
    unsigned short* w1_b   = (unsigned short*)(ws + 8388608);
    unsigned short* w2_b   = (unsigned short*)(ws + 16777216);
    unsigned short* r1     = (unsigned short*)(ws + 25165824);  // xn -> ctx -> xn2
    unsigned short* r2     = (unsigned short*)(ws + 58720256);  // qkv -> h

    unsigned short* xn_b  = r1;
    unsigned short* ctx_b = r1;
    unsigned short* xn2_b = r1;
    unsigned short* qkv_b = r2;
    unsigned short* h_b   = r2;

    cvt_kernel<<<3072, 256, 0, stream>>>(wqkv, wqkv_b, 786432);
    cvt_kernel<<<1024, 256, 0, stream>>>(wo, wo_b, 262144);
    cvt_kernel<<<4096, 256, 0, stream>>>(w1, w1_b, 1048576);
    cvt_kernel<<<4096, 256, 0, stream>>>(w2, w2_b, 1048576);

    ln_kernel<<<16384, 256, 0, stream>>>(x, n1w, n1b, xn_b);
    // QKV: GY=64, GX=12 -> NC=3, MC=32; nt=768, 256 blocks x 3
    gemm_bt<0><<<256, 512, 0, stream>>>(xn_b, wqkv_b, bqkv, nullptr, qkv_b,
                                        16384, 3072, 1024, 3, 3, 32);
    attn_mfma<<<dim3(256, 8), 256, 0, stream>>>(qkv_b, ctx_b);
    // proj: GY=64, GX=4 -> NC=1, MC=32; nt=256, 256 blocks x 1
    gemm_bt<1><<<256, 512, 0, stream>>>(ctx_b, wo_b, bo, x, out,
                                        16384, 1024, 1024, 1, 1, 32);
    ln_kernel<<<16384, 256, 0, stream>>>(out, n2w, n2b, xn2_b);

    // FFN: single pass if h (128 MB @ region2) fits, else 2 row-chunks of 8192 tokens.
    // ws_size is constant across calls -> branch is graph-capture safe.
    if (ws_size >= 192937984ULL) {
        // lin1: GY=64, GX=16 -> NC=4, MC=32; nt=1024, 256 blocks x 4
        gemm_bt<2><<<256, 512, 0, stream>>>(xn2_b, w1_b, b1, nullptr, h_b,
                                            16384, 4096, 1024, 4, 4, 32);
        // lin2: GY=64, GX=4 -> NC=1, MC=32; nt=256, 256 blocks x 1
        gemm_bt<1><<<256, 512, 0, stream>>>(h_b, w2_b, b2, out, out,
                                            16384, 1024, 4096, 1, 1, 32);
    } else {
        for (int c = 0; c < 2; ++c) {
            const size_t row0 = (size_t)c * 8192;
            // lin1 chunk: GY=32 -> MC=16, NC=4; nt=512, 256 blocks x 2
            gemm_bt<2><<<256, 512, 0, stream>>>(xn2_b + row0 * 1024, w1_b, b1,
                                                nullptr, h_b, 8192, 4096, 1024, 2, 4, 16);
            // lin2 chunk: GY=32 -> MC=16, NC=1; nt=128, 128 blocks x 1
            gemm_bt<1><<<128, 512, 0, stream>>>(h_b, w2_b, b2, out + row0 * 1024,
                                                out + row0 * 1024, 8192, 1024, 4096,
                                                1, 1, 16);
        }
    }
}

// Round 6
// 789.750 us; speedup vs baseline: 1.1050x; 1.0834x over previous
//
#include <hip/hip_runtime.h>

// B=16,S=1024,E=1024,F=4096,H=16,D=64. N = B*S = 16384 tokens.
// Pipeline: LN1 -> QKV gemm(bf16 MFMA)+bias -> MFMA flash attn (S^T softmax) ->
//           proj gemm+bias+resid -> d_out -> LN2 -> lin1 gemm+bias+GELU ->
//           lin2 gemm+bias+resid(in-place d_out). FFN single-pass if ws allows, else 2-chunk.
//
// GEMM engine (unchanged from R5): PERSISTENT 256x256 tile, BK=64, 512 thr, dbuf 128 KB
// LDS, 8-phase counted-vmcnt, single barrier/phase, 2D XCD chunking, C^T epilogue.
// R6: attention overhaul — 512 thr / 256 q-rows per block (2x K/V amortization),
// Ks/Ps stride-64 XOR-swizzled LDS (kills the measured 1.47e7 bank conflicts),
// defer-max rescale (T13, THR=8).
//
// Workspace plan:
//   0          wqkv_b  bf16 3072x1024   (6 MB)
//   6291456    wo_b    bf16 1024x1024   (2 MB)
//   8388608    w1_b    bf16 4096x1024   (8 MB)
//   16777216   w2_b    bf16 1024x4096   (8 MB)
//   25165824   region1 (32 MB): xn_b -> ctx_b -> xn2_b
//   58720256   region2: qkv_b (96 MB) -> h (128 MB single-pass if ws_size>=184MiB,
//                                            else 64 MB chunks, 2-pass)
// x1 (fp32) lives in d_out; lin2 updates d_out in place (same-thread R->W).

typedef __attribute__((ext_vector_type(8))) short bf16x8;
typedef __attribute__((ext_vector_type(4))) float f32x4;
typedef __attribute__((ext_vector_type(8))) unsigned short u16x8;
typedef __attribute__((ext_vector_type(4))) unsigned short u16x4;

__device__ __forceinline__ float bf2f(unsigned short u) {
    return __uint_as_float(((unsigned int)u) << 16);
}
__device__ __forceinline__ unsigned short f2bf(float f) {
    unsigned int u = __float_as_uint(f);
    u += 0x7fffu + ((u >> 16) & 1u);   // RNE
    return (unsigned short)(u >> 16);
}
// pack two positive f32 into bf16x2 dword by truncation
__device__ __forceinline__ unsigned int pkbf_trunc(float a, float b) {
    return (__float_as_uint(a) >> 16) | (__float_as_uint(b) & 0xffff0000u);
}

// GELU with A&S 7.1.26 erf (|err| <= 1.5e-7)
__device__ __forceinline__ float fast_gelu(float v) {
    const float x = v * 0.70710678118654752f;
    const float ax = fabsf(x);
    const float t = __builtin_amdgcn_rcpf(fmaf(0.3275911f, ax, 1.0f));
    float p = fmaf(1.061405429f, t, -1.453152027f);
    p = fmaf(p, t, 1.421413741f);
    p = fmaf(p, t, -0.284496736f);
    p = fmaf(p, t, 0.254829592f);
    p = p * t;
    const float e = __expf(-x * x);
    float erfv = fmaf(-p, e, 1.0f);
    erfv = (x < 0.0f) ? -erfv : erfv;
    return 0.5f * v * (1.0f + erfv);
}

// async global->LDS, 16 B per lane; LDS dest is wave-uniform base + lane*16
__device__ __forceinline__ void gload_lds16(const unsigned short* g, unsigned short* l) {
    __builtin_amdgcn_global_load_lds(
        (const __attribute__((address_space(1))) unsigned int*)g,
        (__attribute__((address_space(3))) unsigned int*)l, 16, 0, 0);
}

// compiler memory fence (free) + raw barrier: does NOT drain vmcnt (unlike __syncthreads)
#define FENCE() asm volatile("" ::: "memory")
#define BAR()                         \
    do {                              \
        FENCE();                      \
        __builtin_amdgcn_s_barrier(); \
        FENCE();                      \
    } while (0)
#define VMCNT(n)                                               \
    do {                                                       \
        asm volatile("s_waitcnt vmcnt(" #n ")" ::: "memory");  \
        __builtin_amdgcn_sched_barrier(0);                     \
    } while (0)

// ---------------- fp32 -> bf16 weight conversion ----------------
__global__ __launch_bounds__(256) void cvt_kernel(const float* __restrict__ in,
                                                  unsigned short* __restrict__ out, int n4) {
    int i = blockIdx.x * 256 + threadIdx.x;
    if (i >= n4) return;
    float4 v = ((const float4*)in)[i];
    u16x4 o;
    o[0] = f2bf(v.x); o[1] = f2bf(v.y); o[2] = f2bf(v.z); o[3] = f2bf(v.w);
    ((u16x4*)out)[i] = o;
}

// ---------------- LayerNorm (E=1024), fp32 in -> bf16 out ----------------
__global__ __launch_bounds__(256) void ln_kernel(const float* __restrict__ x,
                                                 const float* __restrict__ w,
                                                 const float* __restrict__ b,
                                                 unsigned short* __restrict__ out) {
    const int row = blockIdx.x;
    const int t = threadIdx.x;
    const float* xr = x + (size_t)row * 1024;
    float4 v = *(const float4*)(xr + t * 4);
    float s = v.x + v.y + v.z + v.w;
    float sq = v.x * v.x + v.y * v.y + v.z * v.z + v.w * v.w;
#pragma unroll
    for (int off = 32; off > 0; off >>= 1) {
        s += __shfl_xor(s, off);
        sq += __shfl_xor(sq, off);
    }
    __shared__ float rs_[4], rq_[4];
    if ((t & 63) == 0) { rs_[t >> 6] = s; rq_[t >> 6] = sq; }
    __syncthreads();
    s = rs_[0] + rs_[1] + rs_[2] + rs_[3];
    sq = rq_[0] + rq_[1] + rq_[2] + rq_[3];
    const float mu = s * (1.0f / 1024.0f);
    const float var = sq * (1.0f / 1024.0f) - mu * mu;
    const float rstd = rsqrtf(var + 1e-5f);
    const int c = t * 4;
    float4 wv = *(const float4*)(w + c);
    float4 bv = *(const float4*)(b + c);
    u16x4 o;
    o[0] = f2bf((v.x - mu) * rstd * wv.x + bv.x);
    o[1] = f2bf((v.y - mu) * rstd * wv.y + bv.y);
    o[2] = f2bf((v.z - mu) * rstd * wv.z + bv.z);
    o[3] = f2bf((v.w - mu) * rstd * wv.w + bv.w);
    *(u16x4*)(out + (size_t)row * 1024 + c) = o;
}

// ---------------- persistent bf16 MFMA GEMM (unchanged from R5) ----------------
template <int EPI>
__global__ __launch_bounds__(512, 2) void gemm_bt(const unsigned short* __restrict__ A,
                                                  const unsigned short* __restrict__ Bt,
                                                  const float* __restrict__ bias,
                                                  const float* __restrict__ resid,
                                                  void* __restrict__ outp,
                                                  int M, int N, int K, int cnt,
                                                  int NC, int MC) {
    __shared__ __align__(16) unsigned short sA[2][256 * 64];
    __shared__ __align__(16) unsigned short sB[2][256 * 64];
    const int t = threadIdx.x;
    const int lane = t & 63;
    const int w = t >> 6;            // 0..7
    const int wm = w >> 2;           // 0..1  (wave M index)
    const int wn = w & 3;            // 0..3  (wave N index)
    const int quad = lane >> 4;
    const int cl = lane & 15;

    const int NB = gridDim.x;
    const int g = blockIdx.x;
    const int lpb = NB >> 3;         // per-XCD block count (l stride per tile step)
    const int xm = (g >> 2) & 1;     // XCD m-row
    const int xn = g & 3;            // XCD n-col
    const int l0 = g >> 3;

#define DECODE(tjv, mB, nB)                                  \
    do {                                                     \
        const int l_ = l0 + (tjv) * lpb;                     \
        const int mi_ = l_ / NC;                             \
        const int ni_ = l_ - mi_ * NC;                       \
        (mB) = (xm * MC + mi_) << 8;                         \
        (nB) = (xn * NC + ni_) << 8;                         \
    } while (0)

    const int swz0 = (quad ^ (cl & 7)) * 16;           // ks=0 chunk byte offset
    const int swz1 = ((quad + 4) ^ (cl & 7)) * 16;     // ks=1 chunk byte offset
    const char* aB0 = (const char*)sA + (wm * 128 + cl) * 128 + swz0;
    const char* aB1 = (const char*)sA + (wm * 128 + cl) * 128 + swz1;
    const char* bB0 = (const char*)sB + (wn * 64 + cl) * 128 + swz0;
    const char* bB1 = (const char*)sB + (wn * 64 + cl) * 128 + swz1;

    const int rl = lane >> 3;
    const size_t o8 = (size_t)8 * K;
    const size_t o128 = (size_t)128 * K;
    const size_t thr = (size_t)(w * 16 + rl) * K + (size_t)(((lane & 7) ^ rl) * 8);

#define STG(gp, sbuf, buf, hf, k0)                                                        \
    do {                                                                                  \
        gload_lds16((gp) + (k0) + thr + (hf) * o128,                                      \
                    &sbuf[buf][((hf) * 128 + w * 16) * 64]);                              \
        gload_lds16((gp) + (k0) + thr + (hf) * o128 + o8,                                 \
                    &sbuf[buf][((hf) * 128 + w * 16 + 8) * 64]);                          \
    } while (0)
#define READ_B8(buf)                                                                      \
    do {                                                                                  \
        _Pragma("unroll") for (int nf_ = 0; nf_ < 4; ++nf_) {                             \
            bfr[nf_][0] = *(const bf16x8*)(bB0 + (buf) * 32768 + nf_ * 2048);             \
            bfr[nf_][1] = *(const bf16x8*)(bB1 + (buf) * 32768 + nf_ * 2048);             \
        }                                                                                 \
    } while (0)
#define READ_A2(buf, mfb)                                                                 \
    do {                                                                                  \
        af[0][0] = *(const bf16x8*)(aB0 + (buf) * 32768 + (mfb) * 2048);                  \
        af[0][1] = *(const bf16x8*)(aB1 + (buf) * 32768 + (mfb) * 2048);                  \
        af[1][0] = *(const bf16x8*)(aB0 + (buf) * 32768 + ((mfb) + 1) * 2048);            \
        af[1][1] = *(const bf16x8*)(aB1 + (buf) * 32768 + ((mfb) + 1) * 2048);            \
    } while (0)
#define MFMA_Q(q)                                                                         \
    do {                                                                                  \
        __builtin_amdgcn_s_setprio(1);                                                    \
        _Pragma("unroll") for (int m_ = 0; m_ < 2; ++m_)                                  \
            _Pragma("unroll") for (int nf_ = 0; nf_ < 4; ++nf_)                           \
                _Pragma("unroll") for (int ks_ = 0; ks_ < 2; ++ks_)                       \
                    acc[2 * (q) + m_][nf_] = __builtin_amdgcn_mfma_f32_16x16x32_bf16(     \
                        bfr[nf_][ks_], af[m_][ks_], acc[2 * (q) + m_][nf_], 0, 0, 0);     \
        __builtin_amdgcn_s_setprio(0);                                                    \
    } while (0)

    f32x4 acc[8][4] = {};
    bf16x8 bfr[4][2];
    bf16x8 af[2][2];

    int mBc, nBc, mBn, nBn;
    DECODE(0, mBc, nBc);
    const unsigned short* gAc = A + (size_t)mBc * K;
    const unsigned short* gBc = Bt + (size_t)nBc * K;
    int kc = 0;
    mBn = mBc; nBn = nBc;
    const unsigned short* gAn = gAc;
    const unsigned short* gBn = gBc;
    int kn = 128;
    int tj = 0;

    STG(gAc, sA, 0, 0, kc); STG(gAc, sA, 0, 1, kc);
    STG(gBc, sB, 0, 0, kc); STG(gBc, sB, 0, 1, kc);
    STG(gBc, sB, 1, 0, kc + 64); STG(gBc, sB, 1, 1, kc + 64);
    VMCNT(4);
    BAR();

    const int TP = cnt * (K >> 7);
    for (int P = 0; P < TP; ++P) {
        const bool more = (P + 1 < TP);
        READ_B8(0); READ_A2(0, 0);
        STG(gAc, sA, 1, 0, kc + 64);
        BAR(); MFMA_Q(0);
        READ_A2(0, 2);
        STG(gAc, sA, 1, 1, kc + 64);
        BAR(); MFMA_Q(1);
        READ_A2(0, 4);
        if (more) STG(gBn, sB, 0, 0, kn);
        BAR(); MFMA_Q(2);
        READ_A2(0, 6);
        if (more) STG(gBn, sB, 0, 1, kn);
        BAR(); MFMA_Q(3);
        if (more) { VMCNT(4); } else { VMCNT(0); }
        BAR();
        READ_B8(1); READ_A2(1, 0);
        if (more) STG(gAn, sA, 0, 0, kn);
        BAR(); MFMA_Q(0);
        READ_A2(1, 2);
        if (more) STG(gAn, sA, 0, 1, kn);
        BAR(); MFMA_Q(1);
        READ_A2(1, 4);
        if (more) STG(gBn, sB, 1, 0, kn + 64);
        BAR(); MFMA_Q(2);
        READ_A2(1, 6);
        if (more) STG(gBn, sB, 1, 1, kn + 64);
        BAR(); MFMA_Q(3);
        if (more) VMCNT(4);
        BAR();

        if (kc + 128 == K) {
#pragma unroll
            for (int mf = 0; mf < 8; ++mf) {
                const int rowg = mBc + wm * 128 + mf * 16 + cl;
                const size_t rb = (size_t)rowg * N;
#pragma unroll
                for (int nf = 0; nf < 4; ++nf) {
                    const int colg = nBc + wn * 64 + nf * 16 + quad * 4;
                    const float4 bv = *(const float4*)(bias + colg);
                    const f32x4 a = acc[mf][nf];
                    const size_t idx = rb + colg;
                    if constexpr (EPI == 0) {
                        u16x4 o;
                        o[0] = f2bf(a[0] + bv.x); o[1] = f2bf(a[1] + bv.y);
                        o[2] = f2bf(a[2] + bv.z); o[3] = f2bf(a[3] + bv.w);
                        *(u16x4*)((unsigned short*)outp + idx) = o;
                    } else if constexpr (EPI == 1) {
                        const float4 rv = *(const float4*)(resid + idx);
                        float4 o;
                        o.x = a[0] + bv.x + rv.x; o.y = a[1] + bv.y + rv.y;
                        o.z = a[2] + bv.z + rv.z; o.w = a[3] + bv.w + rv.w;
                        *(float4*)((float*)outp + idx) = o;
                    } else {
                        u16x4 o;
                        o[0] = f2bf(fast_gelu(a[0] + bv.x));
                        o[1] = f2bf(fast_gelu(a[1] + bv.y));
                        o[2] = f2bf(fast_gelu(a[2] + bv.z));
                        o[3] = f2bf(fast_gelu(a[3] + bv.w));
                        *(u16x4*)((unsigned short*)outp + idx) = o;
                    }
                }
            }
            const f32x4 z = {0.f, 0.f, 0.f, 0.f};
#pragma unroll
            for (int mf = 0; mf < 8; ++mf)
#pragma unroll
                for (int nf = 0; nf < 4; ++nf) acc[mf][nf] = z;
        }
        kc = kn; gAc = gAn; gBc = gBn; mBc = mBn; nBc = nBn;
        kn += 128;
        if (kn >= K) {
            kn = 0;
            ++tj;
            if (tj < cnt) {
                DECODE(tj, mBn, nBn);
                gAn = A + (size_t)mBn * K;
                gBn = Bt + (size_t)nBn * K;
            }
        }
    }
#undef STG
#undef READ_B8
#undef READ_A2
#undef MFMA_Q
#undef DECODE
}

// ---------------- MFMA flash attention, 256 q-rows/block, S^T softmax ----------------
// R6: 512 threads (8 waves, wave w owns q-rows qt*256 + w*32 .. +31, two 16-row subs).
// blockIdx.x = b*16+h, blockIdx.y = 256-row q-tile (4 per (b,h)) -> K/V staged half as
// often per q-row as the 128-row version.
// LDS (XOR chunk-swizzle, GEMM-verified pattern; chunk = 16B, chunk ^= row&7):
//   Ks[64][64] shorts (8 KB)  : K tile, row = key, col = d
//   Vt[64*36]  dwords (9 KB)  : V^T key-pair dwords (unchanged layout)
//   Ps[256][64] shorts (32 KB): P^T rows = q, col = key (wave-private rows, no barrier)
// Softmax: defer-max (THR=8) — rescale pass + alpha shfl only when max grows.
// l rides a 5th PV accumulator vs ones B-frag. 2 barriers/tile.
__global__ __launch_bounds__(512) void attn_mfma(const unsigned short* __restrict__ qkv,
                                                 unsigned short* __restrict__ ctx) {
    __shared__ __align__(16) unsigned short Ks[64 * 64];
    __shared__ __align__(16) unsigned int Vt[64 * 36];
    __shared__ __align__(16) unsigned short Ps[256 * 64];

    const int bh = blockIdx.x;
    const int qt = blockIdx.y;
    const int b = bh >> 4;
    const int h = bh & 15;
    const int t = threadIdx.x;
    const int w = t >> 6;          // 0..7
    const int lane = t & 63;
    const int quad = lane >> 4;
    const int cl = lane & 15;
    const int r7 = cl & 7;         // swizzle key for all row-indexed frag accesses
    const size_t tok0 = (size_t)b * 1024;
    const int qrow0 = qt * 256 + w * 32;

    // Q fragments: operand [idx=cl][k=quad*8 + ks*32] (A/B identical layout)
    bf16x8 aq[2][2];
#pragma unroll
    for (int sub = 0; sub < 2; ++sub) {
        const unsigned short* qp =
            qkv + (tok0 + qrow0 + sub * 16 + cl) * 3072 + h * 64 + quad * 8;
        aq[sub][0] = *(const bf16x8*)(qp);
        aq[sub][1] = *(const bf16x8*)(qp + 32);
    }

    const bf16x8 vones = {0x3F80, 0x3F80, 0x3F80, 0x3F80, 0x3F80, 0x3F80, 0x3F80, 0x3F80};

    // staging indices (512 threads)
    const int r0 = t >> 3;         // K row 0..63
    const int c0 = t & 7;          // K 16B-chunk 0..7
    const int kp = t >> 4;         // V key-pair 0..31
    const int dq = t & 15;         // V d-quad (4 d's)

    // precomputed frag-read bases
    const char* kB0 = (const char*)Ks + cl * 128 + ((quad ^ r7) << 4);
    const char* kB1 = (const char*)Ks + cl * 128 + (((quad + 4) ^ r7) << 4);
    char* pb[2];
#pragma unroll
    for (int sub = 0; sub < 2; ++sub)
        pb[sub] = (char*)Ps + (w * 32 + sub * 16 + cl) * 128;

    f32x4 acc[2][5] = {};          // [sub][j]; j=4 is the l-column
    float m_r[2] = {-3.0e38f, -3.0e38f};

    for (int kt = 0; kt < 16; ++kt) {
        // ---- stage K (swizzled) and V^T ----
        {
            const unsigned short* kg =
                qkv + (tok0 + kt * 64 + r0) * 3072 + 1024 + h * 64 + c0 * 8;
            *(int4*)(Ks + r0 * 64 + ((c0 ^ (r0 & 7)) * 8)) = *(const int4*)(kg);

            const unsigned short* vg =
                qkv + (tok0 + kt * 64 + 2 * kp) * 3072 + 2048 + h * 64 + dq * 4;
            u16x4 v0 = *(const u16x4*)(vg);
            u16x4 v1 = *(const u16x4*)(vg + 3072);
            const int g2 = kp >> 2, wd = kp & 3;
#pragma unroll
            for (int j = 0; j < 4; ++j) {
                const int d = dq * 4 + j;
                Vt[d * 36 + (((g2 ^ (d >> 3)) << 2) | wd)] =
                    ((unsigned int)v1[j] << 16) | (unsigned int)v0[j];
            }
        }
        __syncthreads();

#pragma unroll
        for (int sub = 0; sub < 2; ++sub) {
            // ---- S^T = K·Q^T (operand-swapped MFMA) ----
            f32x4 sc[4] = {};
#pragma unroll
            for (int i = 0; i < 4; ++i) {
                bf16x8 bk0 = *(const bf16x8*)(kB0 + i * 2048);
                bf16x8 bk1 = *(const bf16x8*)(kB1 + i * 2048);
                sc[i] = __builtin_amdgcn_mfma_f32_16x16x32_bf16(bk0, aq[sub][0], sc[i],
                                                                0, 0, 0);
                sc[i] = __builtin_amdgcn_mfma_f32_16x16x32_bf16(bk1, aq[sub][1], sc[i],
                                                                0, 0, 0);
            }
            // ---- softmax for q = cl ----
            float mx0 = fmaxf(fmaxf(sc[0][0], sc[0][1]), fmaxf(sc[0][2], sc[0][3]));
            float mx1 = fmaxf(fmaxf(sc[1][0], sc[1][1]), fmaxf(sc[1][2], sc[1][3]));
            float mx2 = fmaxf(fmaxf(sc[2][0], sc[2][1]), fmaxf(sc[2][2], sc[2][3]));
            float mx3 = fmaxf(fmaxf(sc[3][0], sc[3][1]), fmaxf(sc[3][2], sc[3][3]));
            float rmax = fmaxf(fmaxf(mx0, mx1), fmaxf(mx2, mx3));
            rmax = fmaxf(rmax, __shfl_xor(rmax, 16));
            rmax = fmaxf(rmax, __shfl_xor(rmax, 32));
            const float pm = rmax * 0.125f;
            // defer-max: rescale only when the running max grows by more than THR=8
            if (__any(pm > m_r[sub] + 8.0f)) {
                const float mnew = fmaxf(m_r[sub], pm);
                const float alpha = __expf(m_r[sub] - mnew);
                m_r[sub] = mnew;
                float al[4];
#pragma unroll
                for (int rr = 0; rr < 4; ++rr) al[rr] = __shfl(alpha, quad * 4 + rr, 16);
#pragma unroll
                for (int j = 0; j < 5; ++j)
#pragma unroll
                    for (int rr = 0; rr < 4; ++rr) acc[sub][j][rr] *= al[rr];
            }
            const float mcur = m_r[sub];
            // P = exp(S - m) (bounded by e^8); pack & store swizzled uint2
#pragma unroll
            for (int i = 0; i < 4; ++i) {
                const float p0 = __expf(fmaf(sc[i][0], 0.125f, -mcur));
                const float p1 = __expf(fmaf(sc[i][1], 0.125f, -mcur));
                const float p2 = __expf(fmaf(sc[i][2], 0.125f, -mcur));
                const float p3 = __expf(fmaf(sc[i][3], 0.125f, -mcur));
                uint2 pk;
                pk.x = pkbf_trunc(p0, p1);
                pk.y = pkbf_trunc(p2, p3);
                *(uint2*)(pb[sub] + (((2 * i + (quad >> 1)) ^ r7) << 4) +
                          ((quad & 1) << 3)) = pk;
            }
        }

        // ---- PV (+ l via ones-column) ----
#pragma unroll
        for (int ks = 0; ks < 2; ++ks) {
            bf16x8 bv[4];
#pragma unroll
            for (int j = 0; j < 4; ++j) {
                const int d = j * 16 + cl;
                bv[j] = *(const bf16x8*)(Vt + d * 36 + (((quad + 4 * ks) ^ (d >> 3)) << 2));
            }
#pragma unroll
            for (int sub = 0; sub < 2; ++sub) {
                bf16x8 ap = *(const bf16x8*)(pb[sub] + (((quad + 4 * ks) ^ r7) << 4));
#pragma unroll
                for (int j = 0; j < 4; ++j)
                    acc[sub][j] =
                        __builtin_amdgcn_mfma_f32_16x16x32_bf16(ap, bv[j], acc[sub][j], 0, 0, 0);
                acc[sub][4] =
                    __builtin_amdgcn_mfma_f32_16x16x32_bf16(ap, vones, acc[sub][4], 0, 0, 0);
            }
        }
        __syncthreads();  // Ks/Vt reads done before next staging
    }

    // ---- epilogue: O = acc / l, bf16 store ----
#pragma unroll
    for (int sub = 0; sub < 2; ++sub)
#pragma unroll
        for (int rr = 0; rr < 4; ++rr) {
            const float inv = 1.0f / acc[sub][4][rr];
            const size_t tok = tok0 + qrow0 + sub * 16 + quad * 4 + rr;
#pragma unroll
            for (int j = 0; j < 4; ++j)
                ctx[tok * 1024 + h * 64 + j * 16 + cl] = f2bf(acc[sub][j][rr] * inv);
        }
}

extern "C" void kernel_launch(void* const* d_in, const int* in_sizes, int n_in,
                              void* d_out, int out_size, void* d_ws, size_t ws_size,
                              hipStream_t stream) {
    const float* x    = (const float*)d_in[0];
    const float* wqkv = (const float*)d_in[1];
    const float* bqkv = (const float*)d_in[2];
    const float* wo   = (const float*)d_in[3];
    const float* bo   = (const float*)d_in[4];
    const float* w1   = (const float*)d_in[5];
    const float* b1   = (const float*)d_in[6];
    const float* w2   = (const float*)d_in[7];
    const float* b2   = (const float*)d_in[8];
    const float* n1w  = (const float*)d_in[9];
    const float* n1b  = (const float*)d_in[10];
    const float* n2w  = (const float*)d_in[11];
    const float* n2b  = (const float*)d_in[12];
    float* out = (float*)d_out;   // also serves as x1 (residual stream after attention)

    char* ws = (char*)d_ws;
    unsigned short* wqkv_b = (unsigned short*)(ws);
    unsigned short* wo_b   = (unsigned short*)(ws + 6291456);
    unsigned short* w1_b   = (unsigned short*)(ws + 8388608);
    unsigned short* w2_b   = (unsigned short*)(ws + 16777216);
    unsigned short* r1     = (unsigned short*)(ws + 25165824);  // xn -> ctx -> xn2
    unsigned short* r2     = (unsigned short*)(ws + 58720256);  // qkv -> h

    unsigned short* xn_b  = r1;
    unsigned short* ctx_b = r1;
    unsigned short* xn2_b = r1;
    unsigned short* qkv_b = r2;
    unsigned short* h_b   = r2;

    cvt_kernel<<<3072, 256, 0, stream>>>(wqkv, wqkv_b, 786432);
    cvt_kernel<<<1024, 256, 0, stream>>>(wo, wo_b, 262144);
    cvt_kernel<<<4096, 256, 0, stream>>>(w1, w1_b, 1048576);
    cvt_kernel<<<4096, 256, 0, stream>>>(w2, w2_b, 1048576);

    ln_kernel<<<16384, 256, 0, stream>>>(x, n1w, n1b, xn_b);
    // QKV: GY=64, GX=12 -> NC=3, MC=32; nt=768, 256 blocks x 3
    gemm_bt<0><<<256, 512, 0, stream>>>(xn_b, wqkv_b, bqkv, nullptr, qkv_b,
                                        16384, 3072, 1024, 3, 3, 32);
    attn_mfma<<<dim3(256, 4), 512, 0, stream>>>(qkv_b, ctx_b);
    // proj: GY=64, GX=4 -> NC=1, MC=32; nt=256, 256 blocks x 1
    gemm_bt<1><<<256, 512, 0, stream>>>(ctx_b, wo_b, bo, x, out,
                                        16384, 1024, 1024, 1, 1, 32);
    ln_kernel<<<16384, 256, 0, stream>>>(out, n2w, n2b, xn2_b);

    // FFN: single pass if h (128 MB @ region2) fits, else 2 row-chunks of 8192 tokens.
    // ws_size is constant across calls -> branch is graph-capture safe.
    if (ws_size >= 192937984ULL) {
        // lin1: GY=64, GX=16 -> NC=4, MC=32; nt=1024, 256 blocks x 4
        gemm_bt<2><<<256, 512, 0, stream>>>(xn2_b, w1_b, b1, nullptr, h_b,
                                            16384, 4096, 1024, 4, 4, 32);
        // lin2: GY=64, GX=4 -> NC=1, MC=32; nt=256, 256 blocks x 1
        gemm_bt<1><<<256, 512, 0, stream>>>(h_b, w2_b, b2, out, out,
                                            16384, 1024, 4096, 1, 1, 32);
    } else {
        for (int c = 0; c < 2; ++c) {
            const size_t row0 = (size_t)c * 8192;
            // lin1 chunk: GY=32 -> MC=16, NC=4; nt=512, 256 blocks x 2
            gemm_bt<2><<<256, 512, 0, stream>>>(xn2_b + row0 * 1024, w1_b, b1,
                                                nullptr, h_b, 8192, 4096, 1024, 2, 4, 16);
            // lin2 chunk: GY=32 -> MC=16, NC=1; nt=128, 128 blocks x 1
            gemm_bt<1><<<128, 512, 0, stream>>>(h_b, w2_b, b2, out + row0 * 1024,
                                                out + row0 * 1024, 8192, 1024, 4096,
                                                1, 1, 16);
        }
    }
}